// Round 1
// baseline (19581.573 us; speedup 1.0000x reference)
//
#include <hip/hip_runtime.h>
#include <stdint.h>

#define LSTEPS 2048
#define NB 32
#define IS 128
#define HS 1024
#define NGROUPS 8      // one per XCD (blockIdx % 8 round-robin)
#define WPG 32         // workgroups per group
#define BPG 4          // batch elements per group
#define CPW 32         // hidden columns per WG
#define NTHREADS 256
#define FLAG_SLOTS 64  // flag ring; exact-value match makes reuse safe (skew <= 1 step)

__global__ __launch_bounds__(NTHREADS)
void reservoir_scan(const float* __restrict__ x,
                    const float* __restrict__ h_init,
                    const float* __restrict__ W_in,
                    const float* __restrict__ bias,
                    const float* __restrict__ W_h,
                    float* __restrict__ out,
                    unsigned int* __restrict__ flags) {
  const int b    = blockIdx.x;
  const int g    = b & 7;     // group (likely = XCD)
  const int wg   = b >> 3;    // 0..31 within group
  const int tid  = threadIdx.x;
  const int w    = tid >> 6;  // wave 0..3  (owns 8 hidden cols)
  const int lane = tid & 63;  // k-split lane
  const int jbase = wg * CPW; // hidden-col base of this WG
  const int nbase = g * BPG;  // batch base of this group

  // LDS: region A (8704 floats) is phase-multiplexed:
  //   stage/compute phase: h_lds [4][1024] + x_lds [4][128]
  //   reduce phase:        red [128][68]  (pad 68 -> conflict-free b128 reads)
  // region B: W_in chunk [32][128], loaded once.
  __shared__ __align__(16) float smem[8704 + CPW * IS];
  float* const h_lds   = smem;          // 4096 floats
  float* const x_lds   = smem + 4096;   // 512 floats
  float* const red     = smem;          // 8704 floats
  float* const win_lds = smem + 8704;   // 4096 floats

  // Stage W_in chunk once (rows jbase..jbase+31 contiguous in memory).
  for (int e = tid; e < CPW * IS; e += NTHREADS)
    win_lds[e] = W_in[jbase * IS + e];

  // Reducer threads (tid<128) own output (n = tid>>5, jc = tid&31).
  const float my_bias = (tid < 128) ? bias[jbase + (tid & 31)] : 0.f;

  #pragma unroll 1
  for (int t = 0; t < LSTEPS; ++t) {
    // ---- wait for all 32 producers of step t-1 (wave 0 spins) ----
    if (t > 0) {
      if (w == 0) {
        const unsigned int target = (unsigned int)t;  // value written for step t-1
        const unsigned int* fl =
            flags + ((size_t)(g * FLAG_SLOTS + ((t - 1) & (FLAG_SLOTS - 1))) << 5);
        for (;;) {
          unsigned int v = (lane < WPG)
              ? __hip_atomic_load(&fl[lane], __ATOMIC_RELAXED, __HIP_MEMORY_SCOPE_AGENT)
              : target;
          if (__all(v == target)) break;
          __builtin_amdgcn_s_sleep(1);
        }
      }
    }
    __syncthreads();  // (a) spin done; also protects region A vs prev reduce-reads

    // ---- stage h (16 KB) and x (2 KB) into LDS ----
    if (t > 0) {
      const float* hsrc = out + (size_t)((t - 1) * NB + nbase) * HS;
      for (int e = tid; e < BPG * HS; e += NTHREADS)
        h_lds[e] = __hip_atomic_load(&hsrc[e], __ATOMIC_RELAXED, __HIP_MEMORY_SCOPE_AGENT);
    } else {
      const float* hsrc = h_init + (size_t)nbase * HS;
      for (int e = tid; e < BPG * HS; e += NTHREADS)
        h_lds[e] = hsrc[e];
    }
    {
      const float* xsrc = x + (size_t)(t * NB + nbase) * IS;
      for (int e = tid; e < BPG * IS; e += NTHREADS)
        x_lds[e] = xsrc[e];
    }
    __syncthreads();  // (b) staging visible

    // ---- partial dot products: acc[jj][nn], k split across lanes ----
    float acc[8][4];
    #pragma unroll
    for (int jj = 0; jj < 8; ++jj)
      #pragma unroll
      for (int nn = 0; nn < 4; ++nn) acc[jj][nn] = 0.f;

    // input projection: i = lane*2 .. lane*2+1
    {
      float2 xv[4];
      #pragma unroll
      for (int nn = 0; nn < 4; ++nn)
        xv[nn] = *(const float2*)&x_lds[nn * IS + lane * 2];
      #pragma unroll
      for (int jj = 0; jj < 8; ++jj) {
        const float2 wv = *(const float2*)&win_lds[(w * 8 + jj) * IS + lane * 2];
        #pragma unroll
        for (int nn = 0; nn < 4; ++nn)
          acc[jj][nn] += wv.x * xv[nn].x + wv.y * xv[nn].y;
      }
    }

    // recurrent part: k = u*256 + lane*4 (coalesced float4 W_h stream, L2-resident)
    #pragma unroll
    for (int u = 0; u < 4; ++u) {
      const int k = u * 256 + lane * 4;
      float4 hv[4];
      #pragma unroll
      for (int nn = 0; nn < 4; ++nn)
        hv[nn] = *(const float4*)&h_lds[nn * HS + k];
      #pragma unroll
      for (int jj = 0; jj < 8; ++jj) {
        const float4 wv = *(const float4*)&W_h[(size_t)(jbase + w * 8 + jj) * HS + k];
        #pragma unroll
        for (int nn = 0; nn < 4; ++nn) {
          acc[jj][nn] += wv.x * hv[nn].x;
          acc[jj][nn] += wv.y * hv[nn].y;
          acc[jj][nn] += wv.z * hv[nn].z;
          acc[jj][nn] += wv.w * hv[nn].w;
        }
      }
    }

    __syncthreads();  // (c) h_lds/x_lds reads done -> region A becomes 'red'

    // ---- cross-lane reduction via LDS ----
    #pragma unroll
    for (int jj = 0; jj < 8; ++jj)
      #pragma unroll
      for (int nn = 0; nn < 4; ++nn)
        red[(size_t)(nn * 32 + w * 8 + jj) * 68 + lane] = acc[jj][nn];
    __syncthreads();  // (d)

    if (tid < 128) {
      const int nn = tid >> 5;
      const int jc = tid & 31;
      float s = 0.f;
      const float* r = &red[(size_t)tid * 68];
      #pragma unroll
      for (int q = 0; q < 16; ++q) {
        const float4 v = *(const float4*)&r[q * 4];
        s += (v.x + v.y) + (v.z + v.w);
      }
      s = tanhf(s + my_bias);
      // d_out is both the result and the h-exchange medium.
      float* dst = out + (size_t)(t * NB + nbase + nn) * HS + jbase + jc;
      __hip_atomic_store(dst, s, __ATOMIC_RELAXED, __HIP_MEMORY_SCOPE_AGENT);
    }
    __syncthreads();  // (e) drains vmcnt(0): all slice stores complete before flag

    if (tid == 0) {
      __hip_atomic_store(
          &flags[((size_t)(g * FLAG_SLOTS + (t & (FLAG_SLOTS - 1))) << 5) + wg],
          (unsigned int)(t + 1), __ATOMIC_RELEASE, __HIP_MEMORY_SCOPE_AGENT);
    }
  }
}

extern "C" void kernel_launch(void* const* d_in, const int* in_sizes, int n_in,
                              void* d_out, int out_size, void* d_ws, size_t ws_size,
                              hipStream_t stream) {
  const float* x     = (const float*)d_in[0];
  const float* h0    = (const float*)d_in[1];
  const float* W_in  = (const float*)d_in[2];
  const float* bias  = (const float*)d_in[3];
  const float* W_h   = (const float*)d_in[4];
  float* out = (float*)d_out;
  unsigned int* flags = (unsigned int*)d_ws;  // 8*64*32*4 = 64 KB of ws; poison-safe

  hipLaunchKernelGGL(reservoir_scan, dim3(NGROUPS * WPG), dim3(NTHREADS), 0, stream,
                     x, h0, W_in, bias, W_h, out, flags);
}